// Round 2
// baseline (3207.310 us; speedup 1.0000x reference)
//
#include <hip/hip_runtime.h>
#include <math.h>

#define NN 50000
#define NE 640000

// ---- degree -----------------------------------------------------------------
__global__ void k_deg(const int* __restrict__ dst, float* __restrict__ deg, int E) {
    int e = blockIdx.x * blockDim.x + threadIdx.x;
    if (e < E) atomicAdd(&deg[dst[e]], 1.0f);
}

__global__ void k_deginv(float* __restrict__ deg, int N) {
    int i = blockIdx.x * blockDim.x + threadIdx.x;
    if (i < N) deg[i] = 1.0f / fmaxf(deg[i], 1.0f);
}

// ---- scatter mean: one thread per (edge, 4 channels), dinv folded in --------
template <int LOGC>
__global__ void k_scatter(const float* __restrict__ xin, const int* __restrict__ src,
                          const int* __restrict__ dst, const float* __restrict__ dinv,
                          float* __restrict__ agg, long long total) {
    constexpr int CH4 = 1 << (LOGC - 2);
    long long idx = (long long)blockIdx.x * blockDim.x + threadIdx.x;
    if (idx >= total) return;
    int e  = (int)(idx >> (LOGC - 2));
    int c4 = ((int)idx & (CH4 - 1)) << 2;
    int s = src[e], d = dst[e];
    float di = dinv[d];
    const float4 v = *(const float4*)(xin + ((size_t)s << LOGC) + c4);
    float* a = agg + ((size_t)d << LOGC) + c4;
    atomicAdd(a + 0, v.x * di);
    atomicAdd(a + 1, v.y * di);
    atomicAdd(a + 2, v.z * di);
    atomicAdd(a + 3, v.w * di);
}

// ---- fused SAGE GEMM: out = relu?( agg_scaled@Wl + x@Wr + b ) ---------------
// BM=128 rows/block, BN=Cout (64|128), BK=16. 256 threads: 16 row-groups x 16
// col-groups; per thread TM=8 rows x TN=BN/16 cols register tile.
// A staged k-major in LDS (row dim padded +4 -> conflict-free b128 reads).
template <int CIN, int BN, bool RELU>
__global__ __launch_bounds__(256) void
k_gemm(const float* __restrict__ Agg, const float* __restrict__ X,
       const float* __restrict__ Wl, const float* __restrict__ Wr,
       const float* __restrict__ bias, float* __restrict__ out, int N) {
    constexpr int BM = 128, BK = 16;
    constexpr int TM = 8, TN = BN / 16;

    __shared__ __align__(16) float As[2][BK][BM + 4];   // [mat][k][row]
    __shared__ __align__(16) float Ws[2][BK][BN];       // [mat][k][col]

    const int t  = threadIdx.x;
    const int tc = t & 15;        // col group
    const int tr = t >> 4;        // row group (0..15)
    const int row0 = blockIdx.x * BM;

    float acc[TM][TN] = {};

    for (int k0 = 0; k0 < CIN; k0 += BK) {
        __syncthreads();
        // ---- stage A tiles (both matrices), k-major with transpose ----
#pragma unroll
        for (int p = 0; p < 2; ++p) {
            int idx = t + p * 256;           // 512 float4 per matrix
            int row = idx >> 2;
            int kg  = idx & 3;
            int gr = row0 + row; if (gr > N - 1) gr = N - 1;
            const float4 va = *(const float4*)(Agg + (size_t)gr * CIN + k0 + kg * 4);
            const float4 vx = *(const float4*)(X   + (size_t)gr * CIN + k0 + kg * 4);
            As[0][kg * 4 + 0][row] = va.x;
            As[0][kg * 4 + 1][row] = va.y;
            As[0][kg * 4 + 2][row] = va.z;
            As[0][kg * 4 + 3][row] = va.w;
            As[1][kg * 4 + 0][row] = vx.x;
            As[1][kg * 4 + 1][row] = vx.y;
            As[1][kg * 4 + 2][row] = vx.z;
            As[1][kg * 4 + 3][row] = vx.w;
        }
        // ---- stage W tiles (BK x BN each) ----
#pragma unroll
        for (int idx = t; idx < 4 * BN; idx += 256) {   // 16*BN/4 float4 per mat
            int kk = idx / (BN / 4);
            int c4 = idx % (BN / 4);
            *(float4*)&Ws[0][kk][c4 * 4] = *(const float4*)(Wl + (size_t)(k0 + kk) * BN + c4 * 4);
            *(float4*)&Ws[1][kk][c4 * 4] = *(const float4*)(Wr + (size_t)(k0 + kk) * BN + c4 * 4);
        }
        __syncthreads();
        // ---- compute ----
#pragma unroll
        for (int kk = 0; kk < BK; ++kk) {
            float ag[TM], ax[TM], wl[TN], wr[TN];
            *(float4*)&ag[0] = *(const float4*)&As[0][kk][tr * TM];
            *(float4*)&ag[4] = *(const float4*)&As[0][kk][tr * TM + 4];
            *(float4*)&ax[0] = *(const float4*)&As[1][kk][tr * TM];
            *(float4*)&ax[4] = *(const float4*)&As[1][kk][tr * TM + 4];
#pragma unroll
            for (int c4 = 0; c4 < TN / 4; ++c4) {
                *(float4*)&wl[c4 * 4] = *(const float4*)&Ws[0][kk][tc * TN + c4 * 4];
                *(float4*)&wr[c4 * 4] = *(const float4*)&Ws[1][kk][tc * TN + c4 * 4];
            }
#pragma unroll
            for (int r = 0; r < TM; ++r)
#pragma unroll
                for (int c = 0; c < TN; ++c)
                    acc[r][c] += ag[r] * wl[c] + ax[r] * wr[c];
        }
    }

    // ---- epilogue ----
    float bb[TN];
#pragma unroll
    for (int c = 0; c < TN; ++c) bb[c] = bias[tc * TN + c];
#pragma unroll
    for (int r = 0; r < TM; ++r) {
        int i = row0 + tr * TM + r;
        if (i < N) {
#pragma unroll
            for (int c4 = 0; c4 < TN / 4; ++c4) {
                float4 v;
                v.x = acc[r][c4 * 4 + 0] + bb[c4 * 4 + 0];
                v.y = acc[r][c4 * 4 + 1] + bb[c4 * 4 + 1];
                v.z = acc[r][c4 * 4 + 2] + bb[c4 * 4 + 2];
                v.w = acc[r][c4 * 4 + 3] + bb[c4 * 4 + 3];
                if (RELU) {
                    v.x = fmaxf(v.x, 0.f); v.y = fmaxf(v.y, 0.f);
                    v.z = fmaxf(v.z, 0.f); v.w = fmaxf(v.w, 0.f);
                }
                *(float4*)(out + (size_t)i * BN + tc * TN + c4 * 4) = v;
            }
        }
    }
}

// ---- classifier head: Linear(64,32)+ReLU -> Linear(32,1)+Sigmoid ------------
__global__ void k_classifier(const float* __restrict__ h, const float* __restrict__ Wc1,
                             const float* __restrict__ bc1, const float* __restrict__ Wc2,
                             const float* __restrict__ bc2, float* __restrict__ out, int N) {
    int i = blockIdx.x * blockDim.x + threadIdx.x;
    if (i >= N) return;
    float hrow[64];
#pragma unroll
    for (int k = 0; k < 64; ++k) hrow[k] = h[(size_t)i * 64 + k];
    float acc = bc2[0];
    for (int j = 0; j < 32; ++j) {
        float s = bc1[j];
#pragma unroll
        for (int k = 0; k < 64; ++k) s += hrow[k] * Wc1[k * 32 + j];
        acc += fmaxf(s, 0.f) * Wc2[j];
    }
    out[i] = 1.0f / (1.0f + expf(-acc));
}

extern "C" void kernel_launch(void* const* d_in, const int* in_sizes, int n_in,
                              void* d_out, int out_size, void* d_ws, size_t ws_size,
                              hipStream_t stream) {
    const float* x   = (const float*)d_in[0];
    const int*   ei  = (const int*)d_in[1];   // [2, NE] int32
    const int*   src = ei;
    const int*   dst = ei + NE;
    const float* Wl0 = (const float*)d_in[2];
    const float* Wr0 = (const float*)d_in[3];
    const float* b0  = (const float*)d_in[4];
    const float* Wl1 = (const float*)d_in[5];
    const float* Wr1 = (const float*)d_in[6];
    const float* b1  = (const float*)d_in[7];
    const float* Wl2 = (const float*)d_in[8];
    const float* Wr2 = (const float*)d_in[9];
    const float* b2  = (const float*)d_in[10];
    const float* Wc1 = (const float*)d_in[11];
    const float* bc1 = (const float*)d_in[12];
    const float* Wc2 = (const float*)d_in[13];
    const float* bc2 = (const float*)d_in[14];
    float* out = (float*)d_out;

    char* ws   = (char*)d_ws;
    float* deg = (float*)(ws);                               // NN floats (-> dinv)
    float* agg = (float*)(ws + (size_t)1 * (1 << 20));       // NN*128 floats max
    float* h0  = (float*)(ws + (size_t)28 * (1 << 20));      // NN*128 floats
    float* h1  = (float*)(ws + (size_t)54 * (1 << 20));      // NN*128 floats

    const int B = 256;
    const int GEMM_GRID = (NN + 127) / 128;

    // degree -> dinv (once, reused by all 3 layers)
    hipMemsetAsync(deg, 0, (size_t)NN * sizeof(float), stream);
    k_deg<<<(NE + B - 1) / B, B, 0, stream>>>(dst, deg, NE);
    k_deginv<<<(NN + B - 1) / B, B, 0, stream>>>(deg, NN);

    // layer 0: aggregate x (C=64), GEMM K=64 -> 128, ReLU
    hipMemsetAsync(agg, 0, (size_t)NN * 64 * sizeof(float), stream);
    {
        long long T = (long long)NE * 16;  // E * C/4
        k_scatter<6><<<(unsigned)((T + B - 1) / B), B, 0, stream>>>(x, src, dst, deg, agg, T);
    }
    k_gemm<64, 128, true><<<GEMM_GRID, B, 0, stream>>>(agg, x, Wl0, Wr0, b0, h0, NN);

    // layer 1: aggregate h0 (C=128), GEMM K=128 -> 128, ReLU
    hipMemsetAsync(agg, 0, (size_t)NN * 128 * sizeof(float), stream);
    {
        long long T = (long long)NE * 32;
        k_scatter<7><<<(unsigned)((T + B - 1) / B), B, 0, stream>>>(h0, src, dst, deg, agg, T);
    }
    k_gemm<128, 128, true><<<GEMM_GRID, B, 0, stream>>>(agg, h0, Wl1, Wr1, b1, h1, NN);

    // layer 2: aggregate h1 (C=128), GEMM K=128 -> 64, no ReLU
    hipMemsetAsync(agg, 0, (size_t)NN * 128 * sizeof(float), stream);
    {
        long long T = (long long)NE * 32;
        k_scatter<7><<<(unsigned)((T + B - 1) / B), B, 0, stream>>>(h1, src, dst, deg, agg, T);
    }
    k_gemm<128, 64, false><<<GEMM_GRID, B, 0, stream>>>(agg, h1, Wl2, Wr2, b2, h0, NN);

    // classifier head
    k_classifier<<<(NN + B - 1) / B, B, 0, stream>>>(h0, Wc1, bc1, Wc2, bc2, out, NN);
}

// Round 3
// 768.129 us; speedup vs baseline: 4.1755x; 4.1755x over previous
//
#include <hip/hip_runtime.h>
#include <math.h>

#define NN 50000
#define NE 640000

// ---- degree histogram (int) -------------------------------------------------
__global__ void k_hist(const int* __restrict__ dst, int* __restrict__ deg, int E) {
    int e = blockIdx.x * blockDim.x + threadIdx.x;
    if (e < E) atomicAdd(&deg[dst[e]], 1);
}

__global__ void k_deginv(const int* __restrict__ deg, float* __restrict__ dinv, int N) {
    int i = blockIdx.x * blockDim.x + threadIdx.x;
    if (i < N) dinv[i] = 1.0f / (float)max(deg[i], 1);
}

// ---- single-block exclusive scan over deg -> rs (wave shfl scan) ------------
__global__ __launch_bounds__(1024) void k_scan(const int* __restrict__ deg,
                                               int* __restrict__ rs, int N) {
    __shared__ int wsum[16];
    __shared__ int woff[16];
    __shared__ int carry;
    const int t = threadIdx.x, lane = t & 63, w = t >> 6;
    if (t == 0) carry = 0;
    __syncthreads();
    for (int base = 0; base < N; base += 1024) {
        int i = base + t;
        int v = (i < N) ? deg[i] : 0;
        int incl = v;
#pragma unroll
        for (int off = 1; off < 64; off <<= 1) {
            int nv = __shfl_up(incl, off);
            if (lane >= off) incl += nv;
        }
        if (lane == 63) wsum[w] = incl;
        __syncthreads();
        if (t == 0) {
            int s = 0;
#pragma unroll
            for (int k = 0; k < 16; ++k) { woff[k] = s; s += wsum[k]; }
            wsum[0] = s;  // tile total
        }
        __syncthreads();
        if (i < N) rs[i] = carry + woff[w] + incl - v;   // exclusive
        __syncthreads();
        if (t == 0) carry += wsum[0];
        __syncthreads();
    }
}

// ---- CSR bucket fill: advances rs[d] so that post-fill rs[n] == end(n) ------
__global__ void k_fill(const int* __restrict__ src, const int* __restrict__ dst,
                       int* __restrict__ rs, int* __restrict__ nbr, int E) {
    int e = blockIdx.x * blockDim.x + threadIdx.x;
    if (e < E) {
        int p = atomicAdd(&rs[dst[e]], 1);
        nbr[p] = src[e];
    }
}

// ---- gather aggregation: one wave per node, lanes = channels ----------------
// post-fill rs: beg(n) = (n==0 ? 0 : rs[n-1]), end(n) = rs[n]
template <int LOGC>
__global__ __launch_bounds__(256) void
k_aggregate(const float* __restrict__ xin, const int* __restrict__ nbr,
            const int* __restrict__ rs_end, const float* __restrict__ dinv,
            float* __restrict__ agg, int N) {
    constexpr int C = 1 << LOGC;
    const int gw   = (blockIdx.x * 256 + threadIdx.x) >> 6;
    const int lane = threadIdx.x & 63;
    if (gw >= N) return;
    const int beg = (gw == 0) ? 0 : rs_end[gw - 1];
    const int end = rs_end[gw];
    if (C == 64) {
        float a = 0.f;
        for (int j = beg; j < end; ++j)
            a += xin[((size_t)nbr[j] << 6) + lane];
        agg[((size_t)gw << 6) + lane] = a * dinv[gw];
    } else {
        float a0 = 0.f, a1 = 0.f;
        for (int j = beg; j < end; ++j) {
            const float2 v = *(const float2*)(xin + ((size_t)nbr[j] << 7) + lane * 2);
            a0 += v.x; a1 += v.y;
        }
        const float di = dinv[gw];
        *(float2*)(agg + ((size_t)gw << 7) + lane * 2) = make_float2(a0 * di, a1 * di);
    }
}

// ---- fused SAGE GEMM: out = relu?( agg@Wl + x@Wr + b ) ----------------------
template <int CIN, int BN, bool RELU>
__global__ __launch_bounds__(256) void
k_gemm(const float* __restrict__ Agg, const float* __restrict__ X,
       const float* __restrict__ Wl, const float* __restrict__ Wr,
       const float* __restrict__ bias, float* __restrict__ out, int N) {
    constexpr int BM = 128, BK = 16;
    constexpr int TM = 8, TN = BN / 16;

    __shared__ __align__(16) float As[2][BK][BM + 4];
    __shared__ __align__(16) float Ws[2][BK][BN];

    const int t  = threadIdx.x;
    const int tc = t & 15;
    const int tr = t >> 4;
    const int row0 = blockIdx.x * BM;

    float acc[TM][TN] = {};

    for (int k0 = 0; k0 < CIN; k0 += BK) {
        __syncthreads();
#pragma unroll
        for (int p = 0; p < 2; ++p) {
            int idx = t + p * 256;
            int row = idx >> 2;
            int kg  = idx & 3;
            int gr = row0 + row; if (gr > N - 1) gr = N - 1;
            const float4 va = *(const float4*)(Agg + (size_t)gr * CIN + k0 + kg * 4);
            const float4 vx = *(const float4*)(X   + (size_t)gr * CIN + k0 + kg * 4);
            As[0][kg * 4 + 0][row] = va.x;
            As[0][kg * 4 + 1][row] = va.y;
            As[0][kg * 4 + 2][row] = va.z;
            As[0][kg * 4 + 3][row] = va.w;
            As[1][kg * 4 + 0][row] = vx.x;
            As[1][kg * 4 + 1][row] = vx.y;
            As[1][kg * 4 + 2][row] = vx.z;
            As[1][kg * 4 + 3][row] = vx.w;
        }
#pragma unroll
        for (int idx = t; idx < 4 * BN; idx += 256) {
            int kk = idx / (BN / 4);
            int c4 = idx % (BN / 4);
            *(float4*)&Ws[0][kk][c4 * 4] = *(const float4*)(Wl + (size_t)(k0 + kk) * BN + c4 * 4);
            *(float4*)&Ws[1][kk][c4 * 4] = *(const float4*)(Wr + (size_t)(k0 + kk) * BN + c4 * 4);
        }
        __syncthreads();
#pragma unroll
        for (int kk = 0; kk < BK; ++kk) {
            float ag[TM], ax[TM], wl[TN], wr[TN];
            *(float4*)&ag[0] = *(const float4*)&As[0][kk][tr * TM];
            *(float4*)&ag[4] = *(const float4*)&As[0][kk][tr * TM + 4];
            *(float4*)&ax[0] = *(const float4*)&As[1][kk][tr * TM];
            *(float4*)&ax[4] = *(const float4*)&As[1][kk][tr * TM + 4];
#pragma unroll
            for (int c4 = 0; c4 < TN / 4; ++c4) {
                *(float4*)&wl[c4 * 4] = *(const float4*)&Ws[0][kk][tc * TN + c4 * 4];
                *(float4*)&wr[c4 * 4] = *(const float4*)&Ws[1][kk][tc * TN + c4 * 4];
            }
#pragma unroll
            for (int r = 0; r < TM; ++r)
#pragma unroll
                for (int c = 0; c < TN; ++c)
                    acc[r][c] += ag[r] * wl[c] + ax[r] * wr[c];
        }
    }

    float bb[TN];
#pragma unroll
    for (int c = 0; c < TN; ++c) bb[c] = bias[tc * TN + c];
#pragma unroll
    for (int r = 0; r < TM; ++r) {
        int i = row0 + tr * TM + r;
        if (i < N) {
#pragma unroll
            for (int c4 = 0; c4 < TN / 4; ++c4) {
                float4 v;
                v.x = acc[r][c4 * 4 + 0] + bb[c4 * 4 + 0];
                v.y = acc[r][c4 * 4 + 1] + bb[c4 * 4 + 1];
                v.z = acc[r][c4 * 4 + 2] + bb[c4 * 4 + 2];
                v.w = acc[r][c4 * 4 + 3] + bb[c4 * 4 + 3];
                if (RELU) {
                    v.x = fmaxf(v.x, 0.f); v.y = fmaxf(v.y, 0.f);
                    v.z = fmaxf(v.z, 0.f); v.w = fmaxf(v.w, 0.f);
                }
                *(float4*)(out + (size_t)i * BN + tc * TN + c4 * 4) = v;
            }
        }
    }
}

// ---- classifier head: Linear(64,32)+ReLU -> Linear(32,1)+Sigmoid ------------
__global__ void k_classifier(const float* __restrict__ h, const float* __restrict__ Wc1,
                             const float* __restrict__ bc1, const float* __restrict__ Wc2,
                             const float* __restrict__ bc2, float* __restrict__ out, int N) {
    int i = blockIdx.x * blockDim.x + threadIdx.x;
    if (i >= N) return;
    float hrow[64];
#pragma unroll
    for (int k = 0; k < 64; ++k) hrow[k] = h[(size_t)i * 64 + k];
    float acc = bc2[0];
    for (int j = 0; j < 32; ++j) {
        float s = bc1[j];
#pragma unroll
        for (int k = 0; k < 64; ++k) s += hrow[k] * Wc1[k * 32 + j];
        acc += fmaxf(s, 0.f) * Wc2[j];
    }
    out[i] = 1.0f / (1.0f + expf(-acc));
}

extern "C" void kernel_launch(void* const* d_in, const int* in_sizes, int n_in,
                              void* d_out, int out_size, void* d_ws, size_t ws_size,
                              hipStream_t stream) {
    const float* x   = (const float*)d_in[0];
    const int*   ei  = (const int*)d_in[1];   // [2, NE] int32
    const int*   src = ei;
    const int*   dst = ei + NE;
    const float* Wl0 = (const float*)d_in[2];
    const float* Wr0 = (const float*)d_in[3];
    const float* b0  = (const float*)d_in[4];
    const float* Wl1 = (const float*)d_in[5];
    const float* Wr1 = (const float*)d_in[6];
    const float* b1  = (const float*)d_in[7];
    const float* Wl2 = (const float*)d_in[8];
    const float* Wr2 = (const float*)d_in[9];
    const float* b2  = (const float*)d_in[10];
    const float* Wc1 = (const float*)d_in[11];
    const float* bc1 = (const float*)d_in[12];
    const float* Wc2 = (const float*)d_in[13];
    const float* bc2 = (const float*)d_in[14];
    float* out = (float*)d_out;

    // workspace layout (bytes):
    //   [0,      200K)  dinv   (NN floats)
    //   [256K,   456K)  deg_i  (NN ints)
    //   [512K,   712K)  rs     (NN ints, advances to bucket-ends during fill)
    //   [768K,  3328K)  nbr    (NE ints)
    //   [4M,    29.6M)  agg    (NN*128 floats)
    //   [30M,   55.6M)  h0     (NN*128 floats)
    //   [56M,   81.6M)  h1     (NN*128 floats)
    char*  ws    = (char*)d_ws;
    float* dinv  = (float*)(ws);
    int*   deg_i = (int*)(ws + (size_t)256 * 1024);
    int*   rs    = (int*)(ws + (size_t)512 * 1024);
    int*   nbr   = (int*)(ws + (size_t)768 * 1024);
    float* agg   = (float*)(ws + (size_t)4  * (1 << 20));
    float* h0    = (float*)(ws + (size_t)30 * (1 << 20));
    float* h1    = (float*)(ws + (size_t)56 * (1 << 20));

    const int B = 256;
    const int GEMM_GRID = (NN + 127) / 128;
    const int AGG_GRID  = (NN + 3) / 4;   // 4 waves/block, 1 wave/node

    // ---- CSR build (once per call; edge structure shared by all 3 layers) ----
    hipMemsetAsync(deg_i, 0, (size_t)NN * sizeof(int), stream);
    k_hist<<<(NE + B - 1) / B, B, 0, stream>>>(dst, deg_i, NE);
    k_deginv<<<(NN + B - 1) / B, B, 0, stream>>>(deg_i, dinv, NN);
    k_scan<<<1, 1024, 0, stream>>>(deg_i, rs, NN);
    k_fill<<<(NE + B - 1) / B, B, 0, stream>>>(src, dst, rs, nbr, NE);

    // ---- layer 0: C=64 gather, GEMM K=64 -> 128, ReLU ----
    k_aggregate<6><<<AGG_GRID, B, 0, stream>>>(x, nbr, rs, dinv, agg, NN);
    k_gemm<64, 128, true><<<GEMM_GRID, B, 0, stream>>>(agg, x, Wl0, Wr0, b0, h0, NN);

    // ---- layer 1: C=128 gather, GEMM K=128 -> 128, ReLU ----
    k_aggregate<7><<<AGG_GRID, B, 0, stream>>>(h0, nbr, rs, dinv, agg, NN);
    k_gemm<128, 128, true><<<GEMM_GRID, B, 0, stream>>>(agg, h0, Wl1, Wr1, b1, h1, NN);

    // ---- layer 2: C=128 gather, GEMM K=128 -> 64, no ReLU ----
    k_aggregate<7><<<AGG_GRID, B, 0, stream>>>(h1, nbr, rs, dinv, agg, NN);
    k_gemm<128, 64, false><<<GEMM_GRID, B, 0, stream>>>(agg, h1, Wl2, Wr2, b2, h0, NN);

    // ---- classifier head ----
    k_classifier<<<(NN + B - 1) / B, B, 0, stream>>>(h0, Wc1, bc1, Wc2, bc2, out, NN);
}

// Round 4
// 557.971 us; speedup vs baseline: 5.7482x; 1.3766x over previous
//
#include <hip/hip_runtime.h>
#include <math.h>

#define NN 50000
#define NE 640000

// ---- degree histogram (int) -------------------------------------------------
__global__ void k_hist(const int* __restrict__ dst, int* __restrict__ deg, int E) {
    int e = blockIdx.x * blockDim.x + threadIdx.x;
    if (e < E) atomicAdd(&deg[dst[e]], 1);
}

__global__ void k_deginv(const int* __restrict__ deg, float* __restrict__ dinv, int N) {
    int i = blockIdx.x * blockDim.x + threadIdx.x;
    if (i < N) dinv[i] = 1.0f / (float)max(deg[i], 1);
}

// ---- single-block exclusive scan over deg -> rs (wave shfl scan) ------------
__global__ __launch_bounds__(1024) void k_scan(const int* __restrict__ deg,
                                               int* __restrict__ rs, int N) {
    __shared__ int wsum[16];
    __shared__ int woff[16];
    __shared__ int carry;
    const int t = threadIdx.x, lane = t & 63, w = t >> 6;
    if (t == 0) carry = 0;
    __syncthreads();
    for (int base = 0; base < N; base += 1024) {
        int i = base + t;
        int v = (i < N) ? deg[i] : 0;
        int incl = v;
#pragma unroll
        for (int off = 1; off < 64; off <<= 1) {
            int nv = __shfl_up(incl, off);
            if (lane >= off) incl += nv;
        }
        if (lane == 63) wsum[w] = incl;
        __syncthreads();
        if (t == 0) {
            int s = 0;
#pragma unroll
            for (int k = 0; k < 16; ++k) { woff[k] = s; s += wsum[k]; }
            wsum[0] = s;  // tile total
        }
        __syncthreads();
        if (i < N) rs[i] = carry + woff[w] + incl - v;   // exclusive
        __syncthreads();
        if (t == 0) carry += wsum[0];
        __syncthreads();
    }
}

// ---- CSR bucket fill: advances rs[d] so that post-fill rs[n] == end(n) ------
__global__ void k_fill(const int* __restrict__ src, const int* __restrict__ dst,
                       int* __restrict__ rs, int* __restrict__ nbr, int E) {
    int e = blockIdx.x * blockDim.x + threadIdx.x;
    if (e < E) {
        int p = atomicAdd(&rs[dst[e]], 1);
        nbr[p] = src[e];
    }
}

// ---- gather aggregation: one wave per node, lanes = channels ----------------
template <int LOGC>
__global__ __launch_bounds__(256) void
k_aggregate(const float* __restrict__ xin, const int* __restrict__ nbr,
            const int* __restrict__ rs_end, const float* __restrict__ dinv,
            float* __restrict__ agg, int N) {
    constexpr int C = 1 << LOGC;
    const int gw   = (blockIdx.x * 256 + threadIdx.x) >> 6;
    const int lane = threadIdx.x & 63;
    if (gw >= N) return;
    const int beg = (gw == 0) ? 0 : rs_end[gw - 1];
    const int end = rs_end[gw];
    if (C == 64) {
        float a = 0.f;
        for (int j = beg; j < end; ++j)
            a += xin[((size_t)nbr[j] << 6) + lane];
        agg[((size_t)gw << 6) + lane] = a * dinv[gw];
    } else {
        float a0 = 0.f, a1 = 0.f;
        for (int j = beg; j < end; ++j) {
            const float2 v = *(const float2*)(xin + ((size_t)nbr[j] << 7) + lane * 2);
            a0 += v.x; a1 += v.y;
        }
        const float di = dinv[gw];
        *(float2*)(agg + ((size_t)gw << 7) + lane * 2) = make_float2(a0 * di, a1 * di);
    }
}

// ---- fused SAGE GEMM: out = relu?( agg@Wl + x@Wr + b ) ----------------------
// BM=64 x BN=64 per block (2D grid: rows x col-tiles), BK=16, 256 threads,
// per-thread 4x4 register tile. A staged k-major with +4 pad (<=2-way bank
// aliasing on all LDS ops = free). No spills: ~60 VGPRs.
template <int CIN, int COUT, bool RELU>
__global__ __launch_bounds__(256) void
k_gemm(const float* __restrict__ Agg, const float* __restrict__ X,
       const float* __restrict__ Wl, const float* __restrict__ Wr,
       const float* __restrict__ bias, float* __restrict__ out, int N) {
    constexpr int BM = 64, BN = 64, BK = 16;

    __shared__ __align__(16) float As[2][BK][BM + 4];   // [mat][k][row]
    __shared__ __align__(16) float Ws[2][BK][BN];       // [mat][k][col]

    const int t  = threadIdx.x;
    const int tc = t & 15;          // col group (cols tc*4 .. tc*4+3)
    const int tr = t >> 4;          // row group (rows tr*4 .. tr*4+3)
    const int row0 = blockIdx.x * BM;
    const int col0 = blockIdx.y * BN;

    const int arow = t >> 2;        // 0..63  (A staging row)
    const int akg  = t & 3;         // k-group of 4
    const int wkk  = t >> 4;        // 0..15  (W staging k)
    const int wc4  = (t & 15) * 4;  // W staging col*4

    float acc[4][4] = {};

    for (int k0 = 0; k0 < CIN; k0 += BK) {
        // global loads first (hide latency across the barrier)
        int gr = row0 + arow; if (gr >= N) gr = N - 1;
        const float4 va = *(const float4*)(Agg + (size_t)gr * CIN + k0 + akg * 4);
        const float4 vx = *(const float4*)(X   + (size_t)gr * CIN + k0 + akg * 4);
        const float4 vl = *(const float4*)(Wl + (size_t)(k0 + wkk) * COUT + col0 + wc4);
        const float4 vr = *(const float4*)(Wr + (size_t)(k0 + wkk) * COUT + col0 + wc4);
        __syncthreads();   // WAR: previous iter's reads done before overwrite
        As[0][akg * 4 + 0][arow] = va.x;
        As[0][akg * 4 + 1][arow] = va.y;
        As[0][akg * 4 + 2][arow] = va.z;
        As[0][akg * 4 + 3][arow] = va.w;
        As[1][akg * 4 + 0][arow] = vx.x;
        As[1][akg * 4 + 1][arow] = vx.y;
        As[1][akg * 4 + 2][arow] = vx.z;
        As[1][akg * 4 + 3][arow] = vx.w;
        *(float4*)&Ws[0][wkk][wc4] = vl;
        *(float4*)&Ws[1][wkk][wc4] = vr;
        __syncthreads();
#pragma unroll
        for (int kk = 0; kk < BK; ++kk) {
            float ag[4], ax[4], wl4[4], wr4[4];
            *(float4*)ag  = *(const float4*)&As[0][kk][tr * 4];
            *(float4*)ax  = *(const float4*)&As[1][kk][tr * 4];
            *(float4*)wl4 = *(const float4*)&Ws[0][kk][tc * 4];
            *(float4*)wr4 = *(const float4*)&Ws[1][kk][tc * 4];
#pragma unroll
            for (int r = 0; r < 4; ++r)
#pragma unroll
                for (int c = 0; c < 4; ++c)
                    acc[r][c] += ag[r] * wl4[c] + ax[r] * wr4[c];
        }
    }

    // epilogue: bias (+ReLU), coalesced float4 stores
    float bb[4];
    *(float4*)bb = *(const float4*)(bias + col0 + tc * 4);
#pragma unroll
    for (int r = 0; r < 4; ++r) {
        int i = row0 + tr * 4 + r;
        if (i < N) {
            float4 v;
            v.x = acc[r][0] + bb[0];
            v.y = acc[r][1] + bb[1];
            v.z = acc[r][2] + bb[2];
            v.w = acc[r][3] + bb[3];
            if (RELU) {
                v.x = fmaxf(v.x, 0.f); v.y = fmaxf(v.y, 0.f);
                v.z = fmaxf(v.z, 0.f); v.w = fmaxf(v.w, 0.f);
            }
            *(float4*)(out + (size_t)i * COUT + col0 + tc * 4) = v;
        }
    }
}

// ---- classifier head: Linear(64,32)+ReLU -> Linear(32,1)+Sigmoid ------------
__global__ void k_classifier(const float* __restrict__ h, const float* __restrict__ Wc1,
                             const float* __restrict__ bc1, const float* __restrict__ Wc2,
                             const float* __restrict__ bc2, float* __restrict__ out, int N) {
    int i = blockIdx.x * blockDim.x + threadIdx.x;
    if (i >= N) return;
    float hrow[64];
#pragma unroll
    for (int k = 0; k < 64; ++k) hrow[k] = h[(size_t)i * 64 + k];
    float acc = bc2[0];
    for (int j = 0; j < 32; ++j) {
        float s = bc1[j];
#pragma unroll
        for (int k = 0; k < 64; ++k) s += hrow[k] * Wc1[k * 32 + j];
        acc += fmaxf(s, 0.f) * Wc2[j];
    }
    out[i] = 1.0f / (1.0f + expf(-acc));
}

extern "C" void kernel_launch(void* const* d_in, const int* in_sizes, int n_in,
                              void* d_out, int out_size, void* d_ws, size_t ws_size,
                              hipStream_t stream) {
    const float* x   = (const float*)d_in[0];
    const int*   ei  = (const int*)d_in[1];   // [2, NE] int32
    const int*   src = ei;
    const int*   dst = ei + NE;
    const float* Wl0 = (const float*)d_in[2];
    const float* Wr0 = (const float*)d_in[3];
    const float* b0  = (const float*)d_in[4];
    const float* Wl1 = (const float*)d_in[5];
    const float* Wr1 = (const float*)d_in[6];
    const float* b1  = (const float*)d_in[7];
    const float* Wl2 = (const float*)d_in[8];
    const float* Wr2 = (const float*)d_in[9];
    const float* b2  = (const float*)d_in[10];
    const float* Wc1 = (const float*)d_in[11];
    const float* bc1 = (const float*)d_in[12];
    const float* Wc2 = (const float*)d_in[13];
    const float* bc2 = (const float*)d_in[14];
    float* out = (float*)d_out;

    char*  ws    = (char*)d_ws;
    float* dinv  = (float*)(ws);
    int*   deg_i = (int*)(ws + (size_t)256 * 1024);
    int*   rs    = (int*)(ws + (size_t)512 * 1024);
    int*   nbr   = (int*)(ws + (size_t)768 * 1024);
    float* agg   = (float*)(ws + (size_t)4  * (1 << 20));
    float* h0    = (float*)(ws + (size_t)30 * (1 << 20));
    float* h1    = (float*)(ws + (size_t)56 * (1 << 20));

    const int B = 256;
    const int AGG_GRID = (NN + 3) / 4;       // 4 waves/block, 1 wave/node
    const dim3 G128((NN + 63) / 64, 2);      // COUT=128 -> 2 col tiles
    const dim3 G64 ((NN + 63) / 64, 1);      // COUT=64  -> 1 col tile

    // ---- CSR build (once; edge structure shared by all 3 layers) ----
    hipMemsetAsync(deg_i, 0, (size_t)NN * sizeof(int), stream);
    k_hist<<<(NE + B - 1) / B, B, 0, stream>>>(dst, deg_i, NE);
    k_deginv<<<(NN + B - 1) / B, B, 0, stream>>>(deg_i, dinv, NN);
    k_scan<<<1, 1024, 0, stream>>>(deg_i, rs, NN);
    k_fill<<<(NE + B - 1) / B, B, 0, stream>>>(src, dst, rs, nbr, NE);

    // ---- layer 0: C=64 gather, GEMM K=64 -> 128, ReLU ----
    k_aggregate<6><<<AGG_GRID, B, 0, stream>>>(x, nbr, rs, dinv, agg, NN);
    k_gemm<64, 128, true><<<G128, B, 0, stream>>>(agg, x, Wl0, Wr0, b0, h0, NN);

    // ---- layer 1: C=128 gather, GEMM K=128 -> 128, ReLU ----
    k_aggregate<7><<<AGG_GRID, B, 0, stream>>>(h0, nbr, rs, dinv, agg, NN);
    k_gemm<128, 128, true><<<G128, B, 0, stream>>>(agg, h0, Wl1, Wr1, b1, h1, NN);

    // ---- layer 2: C=128 gather, GEMM K=128 -> 64, no ReLU ----
    k_aggregate<7><<<AGG_GRID, B, 0, stream>>>(h1, nbr, rs, dinv, agg, NN);
    k_gemm<128, 64, false><<<G64, B, 0, stream>>>(agg, h1, Wl2, Wr2, b2, h0, NN);

    // ---- classifier head ----
    k_classifier<<<(NN + B - 1) / B, B, 0, stream>>>(h0, Wc1, bc1, Wc2, bc2, out, NN);
}

// Round 5
// 461.411 us; speedup vs baseline: 6.9511x; 1.2093x over previous
//
#include <hip/hip_runtime.h>
#include <math.h>

#define NN 50000
#define NE 640000

// ---- degree histogram (int) -------------------------------------------------
__global__ void k_hist(const int* __restrict__ dst, int* __restrict__ deg, int E) {
    int e = blockIdx.x * blockDim.x + threadIdx.x;
    if (e < E) atomicAdd(&deg[dst[e]], 1);
}

__global__ void k_deginv(const int* __restrict__ deg, float* __restrict__ dinv, int N) {
    int i = blockIdx.x * blockDim.x + threadIdx.x;
    if (i < N) dinv[i] = 1.0f / (float)max(deg[i], 1);
}

// ---- parallel 3-phase exclusive scan over deg -> rs -------------------------
__global__ __launch_bounds__(1024) void k_chunksum(const int* __restrict__ deg,
                                                   int* __restrict__ bsum, int N) {
    __shared__ int ls[16];
    const int t = threadIdx.x;
    int i = blockIdx.x * 1024 + t;
    int v = (i < N) ? deg[i] : 0;
#pragma unroll
    for (int off = 32; off; off >>= 1) v += __shfl_down(v, off);
    if ((t & 63) == 0) ls[t >> 6] = v;
    __syncthreads();
    if (t == 0) {
        int s = 0;
#pragma unroll
        for (int k = 0; k < 16; ++k) s += ls[k];
        bsum[blockIdx.x] = s;
    }
}

__global__ void k_scanb(int* __restrict__ bsum, int nb) {   // 1 wave, nb <= 64
    const int t = threadIdx.x;
    int v = (t < nb) ? bsum[t] : 0;
    int incl = v;
#pragma unroll
    for (int off = 1; off < 64; off <<= 1) {
        int nv = __shfl_up(incl, off);
        if (t >= off) incl += nv;
    }
    if (t < nb) bsum[t] = incl - v;   // exclusive block offsets
}

__global__ __launch_bounds__(1024) void k_scanfinal(const int* __restrict__ deg,
                                                    const int* __restrict__ boff,
                                                    int* __restrict__ rs, int N) {
    __shared__ int wsum[16], woff[16];
    const int t = threadIdx.x, lane = t & 63, w = t >> 6;
    int i = blockIdx.x * 1024 + t;
    int v = (i < N) ? deg[i] : 0;
    int incl = v;
#pragma unroll
    for (int off = 1; off < 64; off <<= 1) {
        int nv = __shfl_up(incl, off);
        if (lane >= off) incl += nv;
    }
    if (lane == 63) wsum[w] = incl;
    __syncthreads();
    if (t == 0) {
        int s = 0;
#pragma unroll
        for (int k = 0; k < 16; ++k) { woff[k] = s; s += wsum[k]; }
    }
    __syncthreads();
    if (i < N) rs[i] = boff[blockIdx.x] + woff[w] + incl - v;
}

// ---- CSR bucket fill: advances rs[d] so that post-fill rs[n] == end(n) ------
__global__ void k_fill(const int* __restrict__ src, const int* __restrict__ dst,
                       int* __restrict__ rs, int* __restrict__ nbr, int E) {
    int e = blockIdx.x * blockDim.x + threadIdx.x;
    if (e < E) {
        int p = atomicAdd(&rs[dst[e]], 1);
        nbr[p] = src[e];
    }
}

// ---- gather aggregation: one wave per node, lanes = channels, 2x unroll -----
template <int LOGC>
__global__ __launch_bounds__(256) void
k_aggregate(const float* __restrict__ xin, const int* __restrict__ nbr,
            const int* __restrict__ rs_end, const float* __restrict__ dinv,
            float* __restrict__ agg, int N) {
    constexpr int C = 1 << LOGC;
    const int gw   = (blockIdx.x * 256 + threadIdx.x) >> 6;
    const int lane = threadIdx.x & 63;
    if (gw >= N) return;
    const int beg = (gw == 0) ? 0 : rs_end[gw - 1];
    const int end = rs_end[gw];
    if (C == 64) {
        float a = 0.f, b = 0.f;
        int j = beg;
        for (; j + 1 < end; j += 2) {
            int n0 = nbr[j], n1 = nbr[j + 1];
            a += xin[((size_t)n0 << 6) + lane];
            b += xin[((size_t)n1 << 6) + lane];
        }
        if (j < end) a += xin[((size_t)nbr[j] << 6) + lane];
        agg[((size_t)gw << 6) + lane] = (a + b) * dinv[gw];
    } else {
        float a0 = 0.f, a1 = 0.f, b0 = 0.f, b1 = 0.f;
        int j = beg;
        for (; j + 1 < end; j += 2) {
            int n0 = nbr[j], n1 = nbr[j + 1];
            const float2 v0 = *(const float2*)(xin + ((size_t)n0 << 7) + lane * 2);
            const float2 v1 = *(const float2*)(xin + ((size_t)n1 << 7) + lane * 2);
            a0 += v0.x; a1 += v0.y; b0 += v1.x; b1 += v1.y;
        }
        if (j < end) {
            const float2 v = *(const float2*)(xin + ((size_t)nbr[j] << 7) + lane * 2);
            a0 += v.x; a1 += v.y;
        }
        const float di = dinv[gw];
        *(float2*)(agg + ((size_t)gw << 7) + lane * 2) =
            make_float2((a0 + b0) * di, (a1 + b1) * di);
    }
}

// ---- fused SAGE GEMM, merged K: out = act( [agg|x] @ [Wl;Wr] + b ) ----------
// BM=64 x BN=COUT per block, BK=16, 256 threads, double-buffered LDS with ONE
// barrier per K-iter (next tile's global loads issued before compute).
template <int CIN, int COUT, bool RELU>
__global__ __launch_bounds__(256) void
k_gemm(const float* __restrict__ Agg, const float* __restrict__ X,
       const float* __restrict__ Wl, const float* __restrict__ Wr,
       const float* __restrict__ bias, float* __restrict__ out, int N) {
    constexpr int BM = 64, BK = 16;
    constexpr int KT  = (2 * CIN) / BK;      // merged K tiles
    constexpr int NCG = COUT / 4;            // col groups (TN=4)
    constexpr int NRG = 256 / NCG;           // row groups
    constexpr int TM  = BM / NRG;            // 8 (COUT=128) | 4 (COUT=64)
    constexpr int W4  = (BK * NCG) / 256;    // float4/thread for W staging

    __shared__ __align__(16) float As[2][BK][BM + 4];
    __shared__ __align__(16) float Ws[2][BK][COUT];

    const int t  = threadIdx.x;
    const int tc = t % NCG;
    const int tr = t / NCG;
    const int row0 = blockIdx.x * BM;

    const int arow = t >> 2, akg = t & 3;
    int gr = row0 + arow; if (gr >= N) gr = N - 1;

    float4 va;
    float4 vw[W4];

    auto loadTile = [&](int kt) {
        const int mk = kt * BK;                       // merged-k base (never straddles CIN)
        const float* PA = (mk < CIN) ? Agg : X;
        const float* PW = (mk < CIN) ? Wl  : Wr;
        const int kb = (mk < CIN) ? mk : mk - CIN;
        va = *(const float4*)(PA + (size_t)gr * CIN + kb + akg * 4);
#pragma unroll
        for (int p = 0; p < W4; ++p) {
            int idx = t + p * 256;
            int kk  = idx / NCG;
            int c4  = (idx % NCG) * 4;
            vw[p] = *(const float4*)(PW + (size_t)(kb + kk) * COUT + c4);
        }
    };
    auto storeTile = [&](int b) {
        As[b][akg * 4 + 0][arow] = va.x;
        As[b][akg * 4 + 1][arow] = va.y;
        As[b][akg * 4 + 2][arow] = va.z;
        As[b][akg * 4 + 3][arow] = va.w;
#pragma unroll
        for (int p = 0; p < W4; ++p) {
            int idx = t + p * 256;
            int kk  = idx / NCG;
            int c4  = (idx % NCG) * 4;
            *(float4*)&Ws[b][kk][c4] = vw[p];
        }
    };

    float acc[TM][4] = {};

    loadTile(0);
    storeTile(0);
    __syncthreads();

    for (int kt = 0; kt < KT; ++kt) {
        const int buf = kt & 1;
        if (kt + 1 < KT) loadTile(kt + 1);           // overlap with compute below
#pragma unroll
        for (int kk = 0; kk < BK; ++kk) {
            float ar[TM], wf[4];
#pragma unroll
            for (int q = 0; q < TM / 4; ++q)
                *(float4*)&ar[q * 4] = *(const float4*)&As[buf][kk][tr * TM + q * 4];
            *(float4*)wf = *(const float4*)&Ws[buf][kk][tc * 4];
#pragma unroll
            for (int r = 0; r < TM; ++r)
#pragma unroll
                for (int c = 0; c < 4; ++c)
                    acc[r][c] += ar[r] * wf[c];
        }
        if (kt + 1 < KT) {
            storeTile((kt + 1) & 1);   // safe: buf^1 last read before barrier(kt-1)
            __syncthreads();
        }
    }

    float bb[4];
    *(float4*)bb = *(const float4*)(bias + tc * 4);
#pragma unroll
    for (int r = 0; r < TM; ++r) {
        int i = row0 + tr * TM + r;
        if (i < N) {
            float4 v;
            v.x = acc[r][0] + bb[0];
            v.y = acc[r][1] + bb[1];
            v.z = acc[r][2] + bb[2];
            v.w = acc[r][3] + bb[3];
            if (RELU) {
                v.x = fmaxf(v.x, 0.f); v.y = fmaxf(v.y, 0.f);
                v.z = fmaxf(v.z, 0.f); v.w = fmaxf(v.w, 0.f);
            }
            *(float4*)(out + (size_t)i * COUT + tc * 4) = v;
        }
    }
}

// ---- classifier head: Linear(64,32)+ReLU -> Linear(32,1)+Sigmoid ------------
__global__ __launch_bounds__(256) void
k_classifier(const float* __restrict__ h, const float* __restrict__ Wc1,
             const float* __restrict__ bc1, const float* __restrict__ Wc2,
             const float* __restrict__ bc2, float* __restrict__ out, int N) {
    __shared__ float sW1[64 * 32];
    __shared__ float sb1[32];
    __shared__ float sW2[32];
    const int t = threadIdx.x;
    for (int idx = t; idx < 64 * 32; idx += 256) sW1[idx] = Wc1[idx];
    if (t < 32) { sb1[t] = bc1[t]; sW2[t] = Wc2[t]; }
    __syncthreads();
    int i = blockIdx.x * 256 + t;
    if (i >= N) return;
    float hrow[64];
#pragma unroll
    for (int k = 0; k < 64; ++k) hrow[k] = h[(size_t)i * 64 + k];
    float acc = bc2[0];
    for (int j = 0; j < 32; ++j) {
        float s = sb1[j];
#pragma unroll
        for (int k = 0; k < 64; ++k) s += hrow[k] * sW1[k * 32 + j];
        acc += fmaxf(s, 0.f) * sW2[j];
    }
    out[i] = 1.0f / (1.0f + expf(-acc));
}

extern "C" void kernel_launch(void* const* d_in, const int* in_sizes, int n_in,
                              void* d_out, int out_size, void* d_ws, size_t ws_size,
                              hipStream_t stream) {
    const float* x   = (const float*)d_in[0];
    const int*   ei  = (const int*)d_in[1];   // [2, NE] int32
    const int*   src = ei;
    const int*   dst = ei + NE;
    const float* Wl0 = (const float*)d_in[2];
    const float* Wr0 = (const float*)d_in[3];
    const float* b0  = (const float*)d_in[4];
    const float* Wl1 = (const float*)d_in[5];
    const float* Wr1 = (const float*)d_in[6];
    const float* b1  = (const float*)d_in[7];
    const float* Wl2 = (const float*)d_in[8];
    const float* Wr2 = (const float*)d_in[9];
    const float* b2  = (const float*)d_in[10];
    const float* Wc1 = (const float*)d_in[11];
    const float* bc1 = (const float*)d_in[12];
    const float* Wc2 = (const float*)d_in[13];
    const float* bc2 = (const float*)d_in[14];
    float* out = (float*)d_out;

    char*  ws    = (char*)d_ws;
    float* dinv  = (float*)(ws);
    int*   deg_i = (int*)(ws + (size_t)256 * 1024);
    int*   rs    = (int*)(ws + (size_t)512 * 1024);
    int*   bsum  = (int*)(ws + (size_t)712 * 1024);
    int*   nbr   = (int*)(ws + (size_t)768 * 1024);
    float* agg   = (float*)(ws + (size_t)4  * (1 << 20));
    float* h0    = (float*)(ws + (size_t)30 * (1 << 20));
    float* h1    = (float*)(ws + (size_t)56 * (1 << 20));

    const int B = 256;
    const int NB_SCAN = (NN + 1023) / 1024;     // 49
    const int AGG_GRID = (NN + 3) / 4;
    const int GEMM_GRID = (NN + 63) / 64;       // 782 blocks

    // ---- CSR build (once; edge structure shared by all 3 layers) ----
    hipMemsetAsync(deg_i, 0, (size_t)NN * sizeof(int), stream);
    k_hist<<<(NE + B - 1) / B, B, 0, stream>>>(dst, deg_i, NE);
    k_deginv<<<(NN + B - 1) / B, B, 0, stream>>>(deg_i, dinv, NN);
    k_chunksum<<<NB_SCAN, 1024, 0, stream>>>(deg_i, bsum, NN);
    k_scanb<<<1, 64, 0, stream>>>(bsum, NB_SCAN);
    k_scanfinal<<<NB_SCAN, 1024, 0, stream>>>(deg_i, bsum, rs, NN);
    k_fill<<<(NE + B - 1) / B, B, 0, stream>>>(src, dst, rs, nbr, NE);

    // ---- layer 0: C=64 gather, merged GEMM K=128 -> 128, ReLU ----
    k_aggregate<6><<<AGG_GRID, B, 0, stream>>>(x, nbr, rs, dinv, agg, NN);
    k_gemm<64, 128, true><<<GEMM_GRID, B, 0, stream>>>(agg, x, Wl0, Wr0, b0, h0, NN);

    // ---- layer 1: C=128 gather, merged GEMM K=256 -> 128, ReLU ----
    k_aggregate<7><<<AGG_GRID, B, 0, stream>>>(h0, nbr, rs, dinv, agg, NN);
    k_gemm<128, 128, true><<<GEMM_GRID, B, 0, stream>>>(agg, h0, Wl1, Wr1, b1, h1, NN);

    // ---- layer 2: C=128 gather, merged GEMM K=256 -> 64, no ReLU ----
    k_aggregate<7><<<AGG_GRID, B, 0, stream>>>(h1, nbr, rs, dinv, agg, NN);
    k_gemm<128, 64, false><<<GEMM_GRID, B, 0, stream>>>(agg, h1, Wl2, Wr2, b2, h0, NN);

    // ---- classifier head ----
    k_classifier<<<(NN + 255) / 256, B, 0, stream>>>(h0, Wc1, bc1, Wc2, bc2, out, NN);
}